// Round 11
// baseline (16780.872 us; speedup 1.0000x reference)
//
#include <hip/hip_runtime.h>
#include <cstdint>
#include <cmath>

// ============================================================================
// Bidirectional 2-layer GRU, B=64 S=1024 I=H=512, output = last-step concat @ fc.
//   forward : 1024-step recurrence as 1025 graph-replayed STEP KERNELS.
//             Kernel boundary = device-wide barrier + coherence (HSA
//             acquire/release at dispatch edges): NO flags, NO polls, NO
//             fences, NO persistent blocks. Deterministic, hang-proof.
//   backward: only scan index 0 survives => ONE step per layer with h0=0.
//
// Step kernel T (grid 64 x 256): blocks 0-31 (L1, slice s) compute
//   h1_T = gates(x_{T-1}.Wi1, h1_{T-1}.Wh1)          [T = 1..1024]
// blocks 32-63 (L2) compute, one step behind,
//   h2_{T-1} = gates(h1_{T-1}.Wi2, h2_{T-2}.Wh2)     [T = 2..1025]
// A and B stream straight from global (weight image + h rings stay
// Infinity-Cache-resident); no LDS, no __syncthreads in the step kernel.
// Numerics: A in hi+lo bf16 (x from f32 in-reg; h stored as hi/lo planes),
// n-gate weights carry a lo residual plane -> validated absmax 0.0078.
// ============================================================================

typedef __attribute__((ext_vector_type(8))) short bf16x8;
typedef __attribute__((ext_vector_type(4))) float f32x4;
typedef __attribute__((ext_vector_type(4))) unsigned int u32x4;

#define DEV static __device__ __forceinline__

DEV unsigned short f2bf(float f) {
  union { float f; uint32_t u; } v; v.f = f;
  uint32_t u = v.u;
  return (unsigned short)((u + (((u >> 16) & 1u) + 0x7fffu)) >> 16);
}
DEV float bf2f(unsigned short h) {
  union { uint32_t u; float f; } v; v.u = ((uint32_t)h) << 16;
  return v.f;
}
DEV float fsig(float x)  { return 1.f / (1.f + __expf(-x)); }
DEV float ftanh(float x) { return 2.f / (1.f + __expf(-2.f * x)) - 1.f; }

static constexpr int Ss = 1024, Ii = 512;

// ---- workspace layout (bytes) ----
static constexpr size_t WIMG_PER_LS = 131072;                  // 96KB hi + 32KB n-lo
static constexpr size_t OFF_WIMG = 0;
static constexpr size_t WIMG_BYTES = (size_t)64 * WIMG_PER_LS; // 8 MB
static constexpr size_t OFF_H1  = OFF_WIMG + WIMG_BYTES;       // 4 planes x 128KB (hi | lo at +64KB)
static constexpr size_t OFF_H2  = OFF_H1 + 524288;
static constexpr size_t OFF_H2F = OFF_H2 + 524288;             // f32 [64][512]
static constexpr size_t OFF_HB1 = OFF_H2F + 131072;
static constexpr size_t OFF_HB2 = OFF_HB1 + 131072;
static constexpr size_t WS_NEED = OFF_HB2 + 131072;

// ============================================================================
// Weight prep (unchanged): per (layer,slice) image, 65536 bf16 units:
//   [0,24576) Wi-hi: kg*384 + g*128 + cc*8 + kr   | [24576,49152) Wh-hi
//   [49152,57344) Wi n-lo: kg*128 + cc*8 + kr     | [57344,65536) Wh n-lo
// ============================================================================
__global__ __launch_bounds__(256) void prep_weights(const float* __restrict__ Wi,
                                                    const float* __restrict__ Wh,
                                                    unsigned short* __restrict__ img) {
  uint32_t idx = blockIdx.x * 256 + threadIdx.x;          // < 4,194,304
  uint32_t ls = idx >> 16;                                // layer*32+slice
  uint32_t off = idx & 65535u;
  int l = (int)(ls >> 5), s = (int)(ls & 31);
  int m, g, cc, kg, kr;
  bool lo = off >= 49152u;
  if (!lo) {
    m = (int)(off / 24576u); uint32_t r = off % 24576u;
    kg = (int)(r / 384u); r %= 384u;
    int c = (int)(r >> 3); kr = (int)(r & 7u);
    g = c >> 4; cc = c & 15;
  } else {
    uint32_t o2 = off - 49152u;
    m = (int)(o2 >> 13); uint32_t r = o2 & 8191u;
    kg = (int)(r >> 7); r &= 127u;
    cc = (int)(r >> 3); kr = (int)(r & 7u);
    g = 2;
  }
  int h = s * 16 + cc, k = kg * 8 + kr;
  const float* W = m ? Wh : Wi;                           // [L][D][3][512][512], d=0
  float v = W[((size_t)(l * 6 + g) * 512 + k) * 512 + h];
  unsigned short hv = f2bf(v);
  if (lo) hv = f2bf(v - bf2f(hv));
  img[(size_t)ls * 65536 + off] = hv;
}

// zero h rings (h0 = 0 and clean ring planes)
__global__ __launch_bounds__(256) void init_state(uint32_t* __restrict__ hz) {
  int tid = blockIdx.x * 256 + threadIdx.x;
  if (tid < 262144) hz[tid] = 0u;                         // h1+h2 = 1MB
}

#define MFMA(AA, BB, CC) CC = __builtin_amdgcn_mfma_f32_16x16x32_bf16(AA, BB, CC, 0, 0, 0)

// ============================================================================
// One recurrence step (both layers, L2 one step behind). No LDS, no syncs.
// ============================================================================
__global__ __launch_bounds__(256) void gru_step(const float* __restrict__ x,
                                                const float* __restrict__ bias,
                                                unsigned char* __restrict__ ws,
                                                int T) {
  const int tid = threadIdx.x, lane = tid & 63, wv = tid >> 6;
  const int bid = blockIdx.x;
  const int isL2 = bid >> 5;
  const int slice = bid & 31;
  const int l15 = lane & 15, q = lane >> 4;
  if (!isL2 && T > 1024) return;
  if (isL2 && T < 2) return;

  const unsigned short* img = (const unsigned short*)(ws + OFF_WIMG) + (size_t)(isL2 * 32 + slice) * 65536;
  unsigned char* h1b = ws + OFF_H1;
  unsigned char* h2b = ws + OFF_H2;

  const int colg = slice * 16 + l15;
  const int row0 = wv * 16 + q * 4;            // first of this lane's 4 C rows
  const int arow = wv * 16 + l15;              // this lane's A row
  const float b0 = bias[(size_t)(isL2 * 6 + 0) * 512 + colg];
  const float b1 = bias[(size_t)(isL2 * 6 + 1) * 512 + colg];
  const float b2 = bias[(size_t)(isL2 * 6 + 2) * 512 + colg];

  f32x4 ax0{}, ax1{}, ax2{}, ah0{}, ah1{}, ah2{};

  if (!isL2) {
    // ---- L1: ax = x_{T-1}.Wi1 ; ah = h1_{T-1}.Wh1 ----
    const float* xr = x + (size_t)arow * Ss * Ii + (size_t)(T - 1) * Ii;
    const unsigned char* hp = h1b + (size_t)((T - 1) & 3) * 131072;
    const unsigned char* hpa = hp + (size_t)arow * 1024;
#pragma unroll 4
    for (int kk = 0; kk < 16; ++kk) {
      const int kg = kk * 4 + q;
      f32x4 va = *(const f32x4*)(xr + kg * 8);
      f32x4 vb = *(const f32x4*)(xr + kg * 8 + 4);
      bf16x8 xhi, xlo;
#pragma unroll
      for (int e = 0; e < 4; ++e) {
        unsigned short ha = f2bf(va[e]);
        ((unsigned short*)&xhi)[e] = ha;
        ((unsigned short*)&xlo)[e] = f2bf(va[e] - bf2f(ha));
        unsigned short hb_ = f2bf(vb[e]);
        ((unsigned short*)&xhi)[e + 4] = hb_;
        ((unsigned short*)&xlo)[e + 4] = f2bf(vb[e] - bf2f(hb_));
      }
      bf16x8 hhi = *(const bf16x8*)(hpa + (size_t)kg * 16);
      bf16x8 hlo = *(const bf16x8*)(hpa + (size_t)kg * 16 + 65536);
      const unsigned short* wi = img + (size_t)kg * 384 + l15 * 8;           // Wi1 hi
      const unsigned short* wh = img + 24576 + (size_t)kg * 384 + l15 * 8;   // Wh1 hi
      bf16x8 i0 = *(const bf16x8*)(wi);
      bf16x8 i1 = *(const bf16x8*)(wi + 128);
      bf16x8 i2 = *(const bf16x8*)(wi + 256);
      bf16x8 il = *(const bf16x8*)(img + 49152 + (size_t)kg * 128 + l15 * 8);
      bf16x8 w0 = *(const bf16x8*)(wh);
      bf16x8 w1 = *(const bf16x8*)(wh + 128);
      bf16x8 w2 = *(const bf16x8*)(wh + 256);
      bf16x8 wl = *(const bf16x8*)(img + 57344 + (size_t)kg * 128 + l15 * 8);
      MFMA(xhi, i0, ax0); MFMA(xlo, i0, ax0);
      MFMA(xhi, i1, ax1); MFMA(xlo, i1, ax1);
      MFMA(xhi, i2, ax2); MFMA(xlo, i2, ax2);
      MFMA(xhi, il, ax2);
      MFMA(hhi, w0, ah0); MFMA(hlo, w0, ah0);
      MFMA(hhi, w1, ah1); MFMA(hlo, w1, ah1);
      MFMA(hhi, w2, ah2); MFMA(hlo, w2, ah2);
      MFMA(hhi, wl, ah2);
    }
    // ---- gates; h1_T plane write ----
    unsigned char* hd = h1b + (size_t)(T & 3) * 131072;
#pragma unroll
    for (int e = 0; e < 4; ++e) {
      size_t ob = (size_t)(row0 + e) * 1024 + (size_t)colg * 2;
      float hprev = bf2f(*(const unsigned short*)(hp + ob)) +
                    bf2f(*(const unsigned short*)(hp + ob + 65536));
      float rr = fsig(ax0[e] + ah0[e] + b0);
      float zz = fsig(ax1[e] + ah1[e] + b1);
      float nn = ftanh(ax2[e] + b2 + rr * ah2[e]);
      float hn = (1.f - zz) * nn + zz * hprev;
      unsigned short hi = f2bf(hn), lo = f2bf(hn - bf2f(hi));
      *(unsigned short*)(hd + ob) = hi;
      *(unsigned short*)(hd + ob + 65536) = lo;
    }
  } else {
    // ---- L2: ax = h1_{T-1}.Wi2 ; ah = h2_{T-2}.Wh2 ----
    const unsigned char* ap1 = h1b + (size_t)((T - 1) & 3) * 131072 + (size_t)arow * 1024;
    const unsigned char* hp2 = h2b + (size_t)((T - 2) & 3) * 131072;
    const unsigned char* ap2 = hp2 + (size_t)arow * 1024;
#pragma unroll 4
    for (int kk = 0; kk < 16; ++kk) {
      const int kg = kk * 4 + q;
      bf16x8 a1h = *(const bf16x8*)(ap1 + (size_t)kg * 16);
      bf16x8 a1l = *(const bf16x8*)(ap1 + (size_t)kg * 16 + 65536);
      bf16x8 a2h = *(const bf16x8*)(ap2 + (size_t)kg * 16);
      bf16x8 a2l = *(const bf16x8*)(ap2 + (size_t)kg * 16 + 65536);
      const unsigned short* wi = img + (size_t)kg * 384 + l15 * 8;           // Wi2 hi
      const unsigned short* wh = img + 24576 + (size_t)kg * 384 + l15 * 8;   // Wh2 hi
      bf16x8 i0 = *(const bf16x8*)(wi);
      bf16x8 i1 = *(const bf16x8*)(wi + 128);
      bf16x8 i2 = *(const bf16x8*)(wi + 256);
      bf16x8 il = *(const bf16x8*)(img + 49152 + (size_t)kg * 128 + l15 * 8);
      bf16x8 w0 = *(const bf16x8*)(wh);
      bf16x8 w1 = *(const bf16x8*)(wh + 128);
      bf16x8 w2 = *(const bf16x8*)(wh + 256);
      bf16x8 wl = *(const bf16x8*)(img + 57344 + (size_t)kg * 128 + l15 * 8);
      MFMA(a1h, i0, ax0); MFMA(a1l, i0, ax0);
      MFMA(a1h, i1, ax1); MFMA(a1l, i1, ax1);
      MFMA(a1h, i2, ax2); MFMA(a1l, i2, ax2);
      MFMA(a1h, il, ax2);
      MFMA(a2h, w0, ah0); MFMA(a2l, w0, ah0);
      MFMA(a2h, w1, ah1); MFMA(a2l, w1, ah1);
      MFMA(a2h, w2, ah2); MFMA(a2l, w2, ah2);
      MFMA(a2h, wl, ah2);
    }
    // ---- gates; h2_{T-1} plane write (+ h2f at the end) ----
    unsigned char* hd = h2b + (size_t)((T - 1) & 3) * 131072;
    float* h2f = (float*)(ws + OFF_H2F);
#pragma unroll
    for (int e = 0; e < 4; ++e) {
      size_t ob = (size_t)(row0 + e) * 1024 + (size_t)colg * 2;
      float hprev = bf2f(*(const unsigned short*)(hp2 + ob)) +
                    bf2f(*(const unsigned short*)(hp2 + ob + 65536));
      float rr = fsig(ax0[e] + ah0[e] + b0);
      float zz = fsig(ax1[e] + ah1[e] + b1);
      float nn = ftanh(ax2[e] + b2 + rr * ah2[e]);
      float hn = (1.f - zz) * nn + zz * hprev;
      unsigned short hi = f2bf(hn), lo = f2bf(hn - bf2f(hi));
      *(unsigned short*)(hd + ob) = hi;
      *(unsigned short*)(hd + ob + 65536) = lo;
      if (T == 1025) h2f[(size_t)(row0 + e) * 512 + colg] = hn;
    }
  }
}

// ============================================================================
// Backward direction, first scan step only (h0=0): out = (1-sig(xg1))*tanh(xg2).
// ============================================================================
__global__ __launch_bounds__(256) void gru_bstep(const float* __restrict__ inp, long rstride,
                                                 const float* __restrict__ Wi,
                                                 const float* __restrict__ bias,
                                                 float* __restrict__ out) {
  __shared__ float a[8192];                  // [16][512]
  int tid = threadIdx.x;
  int bg = blockIdx.x >> 4, cg = blockIdx.x & 15;
  for (int j = 0; j < 32; ++j) {
    int idx = j * 256 + tid;
    int r = idx >> 9, k = idx & 511;
    a[idx] = inp[(size_t)(bg * 16 + r) * rstride + k];
  }
  __syncthreads();
  int col = cg * 32 + (tid & 31);
  int r0 = tid >> 5;
  float z0 = bias[512 + col], z1 = z0;
  float n0 = bias[1024 + col], n1 = n0;
  const float* W1 = Wi + (size_t)512 * 512;
  const float* W2 = Wi + (size_t)2 * 512 * 512;
  for (int k = 0; k < 512; ++k) {
    float wz = W1[(size_t)k * 512 + col];
    float wn = W2[(size_t)k * 512 + col];
    float a0 = a[r0 * 512 + k], a1 = a[(r0 + 8) * 512 + k];
    z0 += a0 * wz; z1 += a1 * wz;
    n0 += a0 * wn; n1 += a1 * wn;
  }
  float s0 = fsig(z0), s1 = fsig(z1);
  out[(size_t)(bg * 16 + r0) * 512 + col]     = (1.f - s0) * ftanh(n0);
  out[(size_t)(bg * 16 + r0 + 8) * 512 + col] = (1.f - s1) * ftanh(n1);
}

__global__ __launch_bounds__(256) void fc_kernel(const float* __restrict__ h2f,
                                                 const float* __restrict__ hb2,
                                                 const float* __restrict__ fcw,
                                                 const float* __restrict__ fcb,
                                                 float* __restrict__ out) {
  __shared__ float a[16384];                 // [16][1024]
  int tid = threadIdx.x;
  int bg = blockIdx.x >> 4, cg = blockIdx.x & 15;
  for (int j = 0; j < 32; ++j) {
    int idx = j * 256 + tid;
    int r = idx >> 9, k = idx & 511;
    a[r * 1024 + k]       = h2f[(size_t)(bg * 16 + r) * 512 + k];
    a[r * 1024 + 512 + k] = hb2[(size_t)(bg * 16 + r) * 512 + k];
  }
  __syncthreads();
  int col = cg * 32 + (tid & 31);
  int r0 = tid >> 5;
  float s0 = fcb[col], s1 = fcb[col];
  for (int k = 0; k < 1024; ++k) {
    float wvv = fcw[(size_t)k * 512 + col];
    s0 += a[r0 * 1024 + k] * wvv;
    s1 += a[(r0 + 8) * 1024 + k] * wvv;
  }
  out[(size_t)(bg * 16 + r0) * 512 + col]     = s0;
  out[(size_t)(bg * 16 + r0 + 8) * 512 + col] = s1;
}

extern "C" void kernel_launch(void* const* d_in, const int* in_sizes, int n_in,
                              void* d_out, int out_size, void* d_ws, size_t ws_size,
                              hipStream_t stream) {
  const float* x   = (const float*)d_in[0];
  const float* Wi  = (const float*)d_in[1];
  const float* Wh  = (const float*)d_in[2];
  const float* b   = (const float*)d_in[3];
  const float* fcw = (const float*)d_in[4];
  const float* fcb = (const float*)d_in[5];
  float* out = (float*)d_out;
  unsigned char* ws = (unsigned char*)d_ws;
  if (ws_size < WS_NEED) return;   // visible failure (poisoned out), not corruption

  prep_weights<<<16384, 256, 0, stream>>>(Wi, Wh, (unsigned short*)(ws + OFF_WIMG));
  init_state<<<1024, 256, 0, stream>>>((uint32_t*)(ws + OFF_H1));
  for (int T = 1; T <= 1025; ++T)
    gru_step<<<64, 256, 0, stream>>>(x, b, ws, T);
  gru_bstep<<<64, 256, 0, stream>>>(x + (size_t)1023 * 512, (long)Ss * Ii,
                                    Wi + (size_t)3 * 512 * 512, b + 3 * 512,
                                    (float*)(ws + OFF_HB1));
  gru_bstep<<<64, 256, 0, stream>>>((const float*)(ws + OFF_HB1), 512L,
                                    Wi + (size_t)9 * 512 * 512, b + 9 * 512,
                                    (float*)(ws + OFF_HB2));
  fc_kernel<<<64, 256, 0, stream>>>((const float*)(ws + OFF_H2F), (const float*)(ws + OFF_HB2),
                                    fcw, fcb, out);
}

// Round 14
// 13923.749 us; speedup vs baseline: 1.2052x; 1.2052x over previous
//
#include <hip/hip_runtime.h>
#include <cstdint>
#include <cmath>

// ============================================================================
// Bidirectional 2-layer GRU, B=64 S=1024 I=H=512, output = last-step concat @ fc.
//   forward : 1024-step recurrence, persistent kernel, 64 blocks (2 layers x
//             32 col-slices), block = 64 rows x 16 cols, gates in-register.
//   backward: only scan index 0 survives => ONE step per layer with h0=0.
//
// Round-14 = round-8 (best validated, 13.7ms) + ONE change: layer-2's two
// serial GEMMs (h2.Wh2 then h1.Wi2) become a FUSED load pipeline -- all 64
// A-loads interleaved in one counted-vmcnt stream (<=32 outstanding), cutting
// one full coherence-point latency leg from the binding (layer-2) chain.
// All traffic sc0|sc1 coherence-point-direct (zero cache-maintenance ops);
// sched_barrier(0) walls around every asm load/wait group; alive-latch
// timeouts keep it hang-proof. XCD-local approaches abandoned (r6/12/13:
// unverifiable placement/ordering semantics).
// ============================================================================

typedef __attribute__((ext_vector_type(8))) short bf16x8;
typedef __attribute__((ext_vector_type(4))) float f32x4;
typedef __attribute__((ext_vector_type(4))) unsigned int u32x4;

#define DEV static __device__ __forceinline__

DEV unsigned short f2bf(float f) {
  union { float f; uint32_t u; } v; v.f = f;
  uint32_t u = v.u;
  return (unsigned short)((u + (((u >> 16) & 1u) + 0x7fffu)) >> 16);
}
DEV float bf2f(unsigned short h) {
  union { uint32_t u; float f; } v; v.u = ((uint32_t)h) << 16;
  return v.f;
}
DEV float fsig(float x)  { return 1.f / (1.f + __expf(-x)); }
DEV float ftanh(float x) { return 2.f / (1.f + __expf(-2.f * x)) - 1.f; }

static constexpr int Ss = 1024, Ii = 512;

// ---- workspace layout (bytes) ----
static constexpr size_t WIMG_PER_LS = 131072;                  // 96KB hi + 32KB n-lo
static constexpr size_t OFF_WIMG = 0;
static constexpr size_t WIMG_BYTES = (size_t)64 * WIMG_PER_LS; // 8 MB
static constexpr size_t OFF_H1  = OFF_WIMG + WIMG_BYTES;       // 4 planes x 128KB (hi | lo at +64KB)
static constexpr size_t OFF_H2  = OFF_H1 + 524288;
static constexpr size_t OFF_FLG = OFF_H2 + 524288;             // int[64*16] (64B-padded flags)
static constexpr size_t OFF_H2F = OFF_FLG + 4096;              // f32 [64][512]
static constexpr size_t OFF_HB1 = OFF_H2F + 131072;
static constexpr size_t OFF_HB2 = OFF_HB1 + 131072;
static constexpr size_t WS_NEED = OFF_HB2 + 131072;

// ============================================================================
// Weight prep (layout unchanged): per (layer,slice) image, 65536 bf16:
//   [0,49152)     hi : m(2:Wi,Wh)*24576 + kg(64)*384 + (g*16+cc)*8 + kr(8)
//   [49152,65536) n-gate lo residual: m*8192 + kg*128 + cc*8 + kr
// ============================================================================
__global__ __launch_bounds__(256) void prep_weights(const float* __restrict__ Wi,
                                                    const float* __restrict__ Wh,
                                                    unsigned short* __restrict__ img) {
  uint32_t idx = blockIdx.x * 256 + threadIdx.x;          // < 4,194,304
  uint32_t ls = idx >> 16;                                // layer*32+slice
  uint32_t off = idx & 65535u;
  int l = (int)(ls >> 5), s = (int)(ls & 31);
  int m, g, cc, kg, kr;
  bool lo = off >= 49152u;
  if (!lo) {
    m = (int)(off / 24576u); uint32_t r = off % 24576u;
    kg = (int)(r / 384u); r %= 384u;
    int c = (int)(r >> 3); kr = (int)(r & 7u);
    g = c >> 4; cc = c & 15;
  } else {
    uint32_t o2 = off - 49152u;
    m = (int)(o2 >> 13); uint32_t r = o2 & 8191u;
    kg = (int)(r >> 7); r &= 127u;
    cc = (int)(r >> 3); kr = (int)(r & 7u);
    g = 2;
  }
  int h = s * 16 + cc, k = kg * 8 + kr;
  const float* W = m ? Wh : Wi;                           // [L][D][3][512][512], d=0
  float v = W[((size_t)(l * 6 + g) * 512 + k) * 512 + h];
  unsigned short hv = f2bf(v);
  if (lo) hv = f2bf(v - bf2f(hv));
  img[(size_t)ls * 65536 + off] = hv;
}

// zero h rings; flags at i*16: layer0 (i<32) = 0, layer1 = 1
__global__ __launch_bounds__(256) void init_state(uint32_t* __restrict__ hz,
                                                  int* __restrict__ flg) {
  int tid = blockIdx.x * 256 + threadIdx.x;
  if (tid < 262144) hz[tid] = 0u;                         // h1+h2 = 1MB
  if (tid < 1024) flg[tid] = ((tid & 15) == 0 && tid >= 512) ? 1 : 0;
}

#define MFMA(AA, BB, CC) CC = __builtin_amdgcn_mfma_f32_16x16x32_bf16(AA, BB, CC, 0, 0, 0)
#define SB0 __builtin_amdgcn_sched_barrier(0)
#define VMWAIT0  asm volatile("s_waitcnt vmcnt(0)" ::: "memory")
#define VMWAIT8  asm volatile("s_waitcnt vmcnt(8)" ::: "memory")
#define VMWAIT16 asm volatile("s_waitcnt vmcnt(16)" ::: "memory")
#define VMWAIT24 asm volatile("s_waitcnt vmcnt(24)" ::: "memory")
// coherence-point-direct (no L1/L2 allocation, no cache maintenance) ops
#define LD16CP(dst, addr) \
  asm volatile("global_load_dwordx4 %0, %1, off sc0 sc1" : "=&v"(dst) : "v"((const void*)(addr)))
#define ST2CP(addr, val) \
  asm volatile("global_store_short %0, %1, off sc0 sc1" :: "v"((void*)(addr)), "v"((uint32_t)(val)) : "memory")
#define ST4CP(addr, val) \
  asm volatile("global_store_dword %0, %1, off sc0 sc1" :: "v"((void*)(addr)), "v"(val) : "memory")

DEV int pollcp(const int* p) {
  int v;
  asm volatile("global_load_dword %0, %1, off sc0 sc1\ns_waitcnt vmcnt(0)"
               : "=v"(v) : "v"((const void*)p) : "memory");
  return v;
}

// wave-0 combined wait: lane<32 polls layer0 flag[lane] >= tgtA, lane>=32
// polls layer1 flag[lane-32] >= tgtB. Alive-latch timeout: first timeout
// ~0.13s, thereafter 64 spins -> bounded free-run, never hangs.
DEV void wait_combined(int* flg, int tgtA, int tgtB, int lane, int& alive) {
  const int* p = flg + lane * 16;
  const int tgt = (lane < 32) ? tgtA : tgtB;
  const int lim = alive ? (1 << 17) : 64;
  int spins = 0;
  for (;;) {
    int v = pollcp(p);
    if (__all(v >= tgt)) break;
    __builtin_amdgcn_s_sleep(1);
    if (++spins > lim) { alive = 0; break; }
  }
}

// issue 8 pipelined 16B loads into F[FB..FB+7]: 4 (hi,lo) pairs
#define ISSUE8(F, FB, ABASE, BOFF)                                             \
  _Pragma("unroll")                                                            \
  for (int j = 0; j < 4; ++j) {                                                \
    LD16CP(F[(FB) + 2*j],     (ABASE) + (BOFF) + 64 * j);                      \
    LD16CP(F[(FB) + 2*j + 1], (ABASE) + (BOFF) + 64 * j + 65536);              \
  }
// consume 4 (hi,lo) pairs from F[FB..]: B (Wh) from hB regs + n-lo from LDS
#define MFB_REG(F, FB, b, A0, A1, A2)                                          \
  _Pragma("unroll")                                                            \
  for (int j = 0; j < 4; ++j) {                                                \
    const int kk = 4 * (b) + j;                                                \
    const int kg = 16 * (b) + 4 * j + q;                                       \
    bf16x8 ql = *(const bf16x8*)(lds + 98304 + 16384 + (size_t)kg * 256 + (size_t)l15 * 16); \
    MFMA(F[(FB)+2*j], hB[kk*3+0], A0); MFMA(F[(FB)+2*j+1], hB[kk*3+0], A0);    \
    MFMA(F[(FB)+2*j], hB[kk*3+1], A1); MFMA(F[(FB)+2*j+1], hB[kk*3+1], A1);    \
    MFMA(F[(FB)+2*j], hB[kk*3+2], A2); MFMA(F[(FB)+2*j+1], hB[kk*3+2], A2);    \
    MFMA(F[(FB)+2*j], ql, A2);                                                 \
  }
// consume 4 pairs from F[FB..]: B (Wi) from LDS
#define MFB_LDSB(F, FB, b, A0, A1, A2)                                         \
  _Pragma("unroll")                                                            \
  for (int j = 0; j < 4; ++j) {                                                \
    const int kg = 16 * (b) + 4 * j + q;                                       \
    const unsigned char* wb = lds + (size_t)kg * 768 + (size_t)l15 * 16;       \
    bf16x8 q0 = *(const bf16x8*)(wb);                                          \
    bf16x8 q1 = *(const bf16x8*)(wb + 256);                                    \
    bf16x8 q2 = *(const bf16x8*)(wb + 512);                                    \
    bf16x8 ql = *(const bf16x8*)(lds + 98304 + (size_t)kg * 256 + (size_t)l15 * 16); \
    MFMA(F[(FB)+2*j], q0, A0); MFMA(F[(FB)+2*j+1], q0, A0);                    \
    MFMA(F[(FB)+2*j], q1, A1); MFMA(F[(FB)+2*j+1], q1, A1);                    \
    MFMA(F[(FB)+2*j], q2, A2); MFMA(F[(FB)+2*j+1], q2, A2);                    \
    MFMA(F[(FB)+2*j], ql, A2);                                                 \
  }
// single-A pipelined GEMM (layer-1 recurrent path), as in round 8
#define HGEMM(ABASE, A0, A1, A2)                                               \
  {                                                                            \
    bf16x8 fg[32];                                                             \
    SB0; ISSUE8(fg, 0, ABASE, 0)  SB0; ISSUE8(fg, 8, ABASE, 256) SB0;          \
    VMWAIT8; SB0; MFB_REG(fg, 0, 0, A0, A1, A2) SB0;                           \
    ISSUE8(fg, 16, ABASE, 512) SB0; VMWAIT8; SB0; MFB_REG(fg, 8, 1, A0, A1, A2) SB0; \
    ISSUE8(fg, 24, ABASE, 768) SB0; VMWAIT8; SB0; MFB_REG(fg, 16, 2, A0, A1, A2) SB0; \
    VMWAIT0; SB0; MFB_REG(fg, 24, 3, A0, A1, A2) SB0;                          \
  }
// FUSED dual-A pipeline (layer-2): 64 loads in one counted stream, <=32 out.
// A2 (h2_{T-2}, reg-B Wh2) -> ah*; A1 (h1_{T-1}, LDS-B Wi2) -> ax*.
#define HGEMM_FUSED(AB2, AB1)                                                  \
  {                                                                            \
    bf16x8 f2[32], f1[32];                                                     \
    SB0; ISSUE8(f2, 0,  AB2, 0)   SB0; ISSUE8(f1, 0,  AB1, 0)   SB0;           \
    ISSUE8(f2, 8,  AB2, 256) SB0; ISSUE8(f1, 8,  AB1, 256) SB0;                \
    VMWAIT24; SB0; MFB_REG (f2, 0,  0, ah0, ah1, ah2) SB0;                     \
    ISSUE8(f2, 16, AB2, 512) SB0;                                              \
    VMWAIT24; SB0; MFB_LDSB(f1, 0,  0, ax0, ax1, ax2) SB0;                     \
    ISSUE8(f1, 16, AB1, 512) SB0;                                              \
    VMWAIT24; SB0; MFB_REG (f2, 8,  1, ah0, ah1, ah2) SB0;                     \
    ISSUE8(f2, 24, AB2, 768) SB0;                                              \
    VMWAIT24; SB0; MFB_LDSB(f1, 8,  1, ax0, ax1, ax2) SB0;                     \
    ISSUE8(f1, 24, AB1, 768) SB0;                                              \
    VMWAIT24; SB0; MFB_REG (f2, 16, 2, ah0, ah1, ah2) SB0;                     \
    VMWAIT16; SB0; MFB_LDSB(f1, 16, 2, ax0, ax1, ax2) SB0;                     \
    VMWAIT8;  SB0; MFB_REG (f2, 24, 3, ah0, ah1, ah2) SB0;                     \
    VMWAIT0;  SB0; MFB_LDSB(f1, 24, 3, ax0, ax1, ax2) SB0;                     \
  }
// x_t . Wi1 : plain cached loads (read-only x), hi/lo built in-reg, B from LDS
#define XGEMM(T0)                                                              \
  {                                                                            \
    const float* xr = xr0 + (size_t)(T0) * Ii;                                 \
    _Pragma("unroll 4")                                                        \
    for (int kk = 0; kk < 16; ++kk) {                                          \
      const int kg = kk * 4 + q;                                               \
      f32x4 va = *(const f32x4*)(xr + kg * 8);                                 \
      f32x4 vb = *(const f32x4*)(xr + kg * 8 + 4);                             \
      bf16x8 ahi, alo;                                                         \
      _Pragma("unroll")                                                        \
      for (int e = 0; e < 4; ++e) {                                            \
        unsigned short ha = f2bf(va[e]);                                       \
        ((unsigned short*)&ahi)[e] = ha;                                       \
        ((unsigned short*)&alo)[e] = f2bf(va[e] - bf2f(ha));                   \
        unsigned short hb_ = f2bf(vb[e]);                                      \
        ((unsigned short*)&ahi)[e + 4] = hb_;                                  \
        ((unsigned short*)&alo)[e + 4] = f2bf(vb[e] - bf2f(hb_));              \
      }                                                                        \
      const unsigned char* wb = lds + (size_t)kg * 768 + (size_t)l15 * 16;     \
      bf16x8 q0 = *(const bf16x8*)(wb);                                        \
      bf16x8 q1 = *(const bf16x8*)(wb + 256);                                  \
      bf16x8 q2 = *(const bf16x8*)(wb + 512);                                  \
      bf16x8 ql = *(const bf16x8*)(lds + 98304 + (size_t)kg * 256 + (size_t)l15 * 16); \
      MFMA(ahi, q0, ax0); MFMA(alo, q0, ax0);                                  \
      MFMA(ahi, q1, ax1); MFMA(alo, q1, ax1);                                  \
      MFMA(ahi, q2, ax2); MFMA(alo, q2, ax2);                                  \
      MFMA(ahi, ql, ax2);                                                      \
    }                                                                          \
  }

// ============================================================================
// Persistent forward recurrence. LDS = 128KB weight image only.
// ============================================================================
__global__ __launch_bounds__(256, 1) void gru_persistent(const float* __restrict__ x,
                                                         const float* __restrict__ bias,
                                                         unsigned char* __restrict__ ws) {
  __shared__ unsigned char lds[131072];
  const int tid = threadIdx.x, lane = tid & 63, wv = tid >> 6;
  const int bid = blockIdx.x;
  const int xcd = bid & 7;
  const int layer = xcd >> 2;
  const int slice = (xcd & 3) * 8 + (bid >> 3);
  const int l15 = lane & 15, q = lane >> 4;

  { // stage this block's 128KB weight image into LDS once
    const u32x4* src = (const u32x4*)(ws + OFF_WIMG + (size_t)(layer * 32 + slice) * WIMG_PER_LS);
    u32x4* dst = (u32x4*)lds;
    for (int i = tid; i < 8192; i += 256) dst[i] = src[i];
  }
  __syncthreads();

  // recurrent-side (Wh) hi B-fragments: 16 kk x 3 gates
  bf16x8 hB[48];
#pragma unroll
  for (int kk = 0; kk < 16; ++kk) {
    const int kg = kk * 4 + q;
    const unsigned char* wb = lds + 49152 + (size_t)kg * 768 + (size_t)l15 * 16;
    hB[kk * 3 + 0] = *(const bf16x8*)(wb);
    hB[kk * 3 + 1] = *(const bf16x8*)(wb + 256);
    hB[kk * 3 + 2] = *(const bf16x8*)(wb + 512);
  }

  unsigned char* h1b = ws + OFF_H1;
  unsigned char* h2b = ws + OFF_H2;
  int* flg = (int*)(ws + OFF_FLG);
  float* h2f = (float*)(ws + OFF_H2F);

  const int colg = slice * 16 + l15;
  const int row0 = wv * 16 + q * 4;            // first of this lane's 4 C rows
  const int arow = wv * 16 + l15;              // this lane's A row
  const float b0 = bias[(size_t)(layer * 6 + 0) * 512 + colg];
  const float b1 = bias[(size_t)(layer * 6 + 1) * 512 + colg];
  const float b2 = bias[(size_t)(layer * 6 + 2) * 512 + colg];

  int* myflag = flg + (layer * 32 + slice) * 16;
  f32x4 hprev{0.f, 0.f, 0.f, 0.f};
  int alive = 1;

  if (layer == 0) {
    const float* xr0 = x + (size_t)arow * Ss * Ii;
    f32x4 ax0{}, ax1{}, ax2{};
    XGEMM(0)                                   // prologue: x_0 . Wi1
    for (int T = 1; T <= 1024; ++T) {
      // wait: peers' h1_{T-1} ready AND layer-2 past h1_{T-4} (plane reuse)
      if (wv == 0) wait_combined(flg, T - 1, T - 3, lane, alive);
      __syncthreads();
      f32x4 ah0{}, ah1{}, ah2{};
      const unsigned char* ab = h1b + (size_t)((T - 1) & 3) * 131072 + (size_t)arow * 1024 + (size_t)q * 16;
      HGEMM(ab, ah0, ah1, ah2)
      // gates in-register; sc0sc1 store h1_T
      unsigned char* hd = h1b + (size_t)(T & 3) * 131072;
#pragma unroll
      for (int e = 0; e < 4; ++e) {
        float rr = fsig(ax0[e] + ah0[e] + b0);
        float zz = fsig(ax1[e] + ah1[e] + b1);
        float nn = ftanh(ax2[e] + b2 + rr * ah2[e]);
        float hn = (1.f - zz) * nn + zz * hprev[e];
        hprev[e] = hn;
        unsigned short hi = f2bf(hn), lo = f2bf(hn - bf2f(hi));
        size_t ob = (size_t)(row0 + e) * 1024 + (size_t)colg * 2;
        ST2CP(hd + ob, hi); ST2CP(hd + ob + 65536, lo);
      }
      VMWAIT0;                                 // stores acked at coherence point
      __syncthreads();                         // all waves done
      if (tid == 0) ST4CP(myflag, T);
      // next step's x GEMM (plain loads, outside the counted-vmcnt region)
      ax0 = f32x4{}; ax1 = f32x4{}; ax2 = f32x4{};
      if (T < 1024) XGEMM(T)
    }
  } else {
    // layer 2, one step behind: at iter T computes h2_{T-1}
    for (int T = 2; T <= 1025; ++T) {
      if (wv == 0) wait_combined(flg, T - 1, T - 1, lane, alive);
      __syncthreads();
      f32x4 ax0{}, ax1{}, ax2{}, ah0{}, ah1{}, ah2{};
      const unsigned char* ab2 = h2b + (size_t)((T - 2) & 3) * 131072 + (size_t)arow * 1024 + (size_t)q * 16;
      const unsigned char* ab1 = h1b + (size_t)((T - 1) & 3) * 131072 + (size_t)arow * 1024 + (size_t)q * 16;
      HGEMM_FUSED(ab2, ab1)                    // ah = h2.Wh2 ; ax = h1.Wi2 (one pipeline)
      unsigned char* hd = h2b + (size_t)((T - 1) & 3) * 131072;
#pragma unroll
      for (int e = 0; e < 4; ++e) {
        float rr = fsig(ax0[e] + ah0[e] + b0);
        float zz = fsig(ax1[e] + ah1[e] + b1);
        float nn = ftanh(ax2[e] + b2 + rr * ah2[e]);
        float hn = (1.f - zz) * nn + zz * hprev[e];
        hprev[e] = hn;
        unsigned short hi = f2bf(hn), lo = f2bf(hn - bf2f(hi));
        size_t ob = (size_t)(row0 + e) * 1024 + (size_t)colg * 2;
        ST2CP(hd + ob, hi); ST2CP(hd + ob + 65536, lo);
        if (T == 1025) h2f[(size_t)(row0 + e) * 512 + colg] = hn;
      }
      VMWAIT0;
      __syncthreads();
      if (tid == 0) ST4CP(myflag, T);
    }
  }
}

// ============================================================================
// Backward direction, first scan step only (h0=0): out = (1-sig(xg1))*tanh(xg2).
// ============================================================================
__global__ __launch_bounds__(256) void gru_bstep(const float* __restrict__ inp, long rstride,
                                                 const float* __restrict__ Wi,
                                                 const float* __restrict__ bias,
                                                 float* __restrict__ out) {
  __shared__ float a[8192];                  // [16][512]
  int tid = threadIdx.x;
  int bg = blockIdx.x >> 4, cg = blockIdx.x & 15;
  for (int j = 0; j < 32; ++j) {
    int idx = j * 256 + tid;
    int r = idx >> 9, k = idx & 511;
    a[idx] = inp[(size_t)(bg * 16 + r) * rstride + k];
  }
  __syncthreads();
  int col = cg * 32 + (tid & 31);
  int r0 = tid >> 5;
  float z0 = bias[512 + col], z1 = z0;
  float n0 = bias[1024 + col], n1 = n0;
  const float* W1 = Wi + (size_t)512 * 512;
  const float* W2 = Wi + (size_t)2 * 512 * 512;
  for (int k = 0; k < 512; ++k) {
    float wz = W1[(size_t)k * 512 + col];
    float wn = W2[(size_t)k * 512 + col];
    float a0 = a[r0 * 512 + k], a1 = a[(r0 + 8) * 512 + k];
    z0 += a0 * wz; z1 += a1 * wz;
    n0 += a0 * wn; n1 += a1 * wn;
  }
  float s0 = fsig(z0), s1 = fsig(z1);
  out[(size_t)(bg * 16 + r0) * 512 + col]     = (1.f - s0) * ftanh(n0);
  out[(size_t)(bg * 16 + r0 + 8) * 512 + col] = (1.f - s1) * ftanh(n1);
}

__global__ __launch_bounds__(256) void fc_kernel(const float* __restrict__ h2f,
                                                 const float* __restrict__ hb2,
                                                 const float* __restrict__ fcw,
                                                 const float* __restrict__ fcb,
                                                 float* __restrict__ out) {
  __shared__ float a[16384];                 // [16][1024]
  int tid = threadIdx.x;
  int bg = blockIdx.x >> 4, cg = blockIdx.x & 15;
  for (int j = 0; j < 32; ++j) {
    int idx = j * 256 + tid;
    int r = idx >> 9, k = idx & 511;
    a[r * 1024 + k]       = h2f[(size_t)(bg * 16 + r) * 512 + k];
    a[r * 1024 + 512 + k] = hb2[(size_t)(bg * 16 + r) * 512 + k];
  }
  __syncthreads();
  int col = cg * 32 + (tid & 31);
  int r0 = tid >> 5;
  float s0 = fcb[col], s1 = fcb[col];
  for (int k = 0; k < 1024; ++k) {
    float wvv = fcw[(size_t)k * 512 + col];
    s0 += a[r0 * 1024 + k] * wvv;
    s1 += a[(r0 + 8) * 1024 + k] * wvv;
  }
  out[(size_t)(bg * 16 + r0) * 512 + col]     = s0;
  out[(size_t)(bg * 16 + r0 + 8) * 512 + col] = s1;
}

extern "C" void kernel_launch(void* const* d_in, const int* in_sizes, int n_in,
                              void* d_out, int out_size, void* d_ws, size_t ws_size,
                              hipStream_t stream) {
  const float* x   = (const float*)d_in[0];
  const float* Wi  = (const float*)d_in[1];
  const float* Wh  = (const float*)d_in[2];
  const float* b   = (const float*)d_in[3];
  const float* fcw = (const float*)d_in[4];
  const float* fcb = (const float*)d_in[5];
  float* out = (float*)d_out;
  unsigned char* ws = (unsigned char*)d_ws;
  if (ws_size < WS_NEED) return;   // visible failure (poisoned out), not corruption

  prep_weights<<<16384, 256, 0, stream>>>(Wi, Wh, (unsigned short*)(ws + OFF_WIMG));
  init_state<<<1024, 256, 0, stream>>>((uint32_t*)(ws + OFF_H1), (int*)(ws + OFF_FLG));
  gru_persistent<<<64, 256, 0, stream>>>(x, b, ws);
  gru_bstep<<<64, 256, 0, stream>>>(x + (size_t)1023 * 512, (long)Ss * Ii,
                                    Wi + (size_t)3 * 512 * 512, b + 3 * 512,
                                    (float*)(ws + OFF_HB1));
  gru_bstep<<<64, 256, 0, stream>>>((const float*)(ws + OFF_HB1), 512L,
                                    Wi + (size_t)9 * 512 * 512, b + 9 * 512,
                                    (float*)(ws + OFF_HB2));
  fc_kernel<<<64, 256, 0, stream>>>((const float*)(ws + OFF_H2F), (const float*)(ws + OFF_HB2),
                                    fcw, fcb, out);
}